// Round 6
// baseline (2311.751 us; speedup 1.0000x reference)
//
#include <hip/hip_runtime.h>
#include <math.h>

#define NB 4
#define NW 24
#define H 512
#define H2 1024
#define H5 2560
#define NCELL 300   // n*(n+1)/2 valid cells per batch

// total workspace floats needed
#define NEED_FLOATS (2u*H*H5 + 2u*NB*NCELL*H + NB*NCELL + 2u*NB*NCELL*H5 + NB*NCELL*H2)
#define NEED_BYTES  ((size_t)NEED_FLOATS * 4u)

// Private fallback workspace: allocated ONCE at library load (outside
// kernel_launch, so graph capture never sees the hipMalloc). d_ws proved too
// small in round 1 (44.9MB layout corrupted adjacent harness allocations).
static float* g_buf = nullptr;
__attribute__((constructor)) static void dio_alloc_ws(){
  (void)hipMalloc((void**)&g_buf, NEED_BYTES + (1u<<20));
}

__device__ __forceinline__ int coff(int l){ return l*NW - (l*(l-1))/2; }
__device__ __forceinline__ float sigm(float x){ return 1.f/(1.f+__expf(-x)); }
__device__ __forceinline__ float ftanh(float x){ return 1.f - 2.f/(__expf(2.f*x)+1.f); }

// async global->LDS DMA: each lane contributes 4 B; LDS side is
// wave-uniform base + lane*4 (m104/m108 semantics). No VGPR held open.
typedef const __attribute__((address_space(1))) unsigned int gu32;
typedef __attribute__((address_space(3))) unsigned int lu32;
__device__ __forceinline__ void dma_row(const float* g, float* l){
  __builtin_amdgcn_global_load_lds((gu32*)g, (lu32*)l, 4, 0, 0);
}

// ---- transpose Wi [2560,512] -> WiT [512,2560] (and Ws) for coalesced proj reads
__global__ void k_transpose(const float* __restrict__ Wi, const float* __restrict__ Ws,
                            float* __restrict__ WiT, float* __restrict__ WsT){
  const float* in  = blockIdx.z ? Ws  : Wi;
  float*       out = blockIdx.z ? WsT : WiT;
  __shared__ float tile[32][33];
  int tr = blockIdx.y*32, tc = blockIdx.x*32;
  int tx = threadIdx.x, ty = threadIdx.y;
  #pragma unroll
  for (int i=0;i<32;i+=8)
    tile[ty+i][tx] = in[(size_t)(tr+ty+i)*H + tc+tx];
  __syncthreads();
  #pragma unroll
  for (int i=0;i<32;i+=8)
    out[(size_t)(tc+ty+i)*H5 + tr+tx] = tile[tx][ty+i];
}

// ---- leaves: cell (i,0): H = seq[i,:512], C = seq[i,512:], S = 0
__global__ void k_leaf(const float* __restrict__ seqt, float* __restrict__ cH,
                       float* __restrict__ cC, float* __restrict__ cS){
  int tid = blockIdx.x*256 + threadIdx.x;
  if (tid >= NB*NW*H) return;
  int b = tid/(NW*H); int r = tid%(NW*H); int i = r/H; int d = r%H;
  int cell = b*NCELL + i;                 // coff(0)==0
  cH[(size_t)cell*H + d] = seqt[(size_t)(b*NW+i)*H2 + d];
  cC[(size_t)cell*H + d] = seqt[(size_t)(b*NW+i)*H2 + H + d];
  if (d==0) cS[cell] = 0.f;
}

// ---- per-cell projections for diagonal d:
//   PI = H@Wi^T + bi + ins_bias ; PS = H@Ws^T + bs ; U = [H,C]^T Wbil
// Block = 1 wave; thread owns column j = group*64+t for 8 m-rows.
// grid.x = 96 j-groups (0-39: PI, 40-79: PS, 80-95: U), grid.y = m-tiles of 8.
// Round 4/5 lesson: register prefetch of weights gets serialized by the
// compiler (~375cy exposed per load -> 80us/block). Fix: weights arrive via
// async global_load_lds double-buffer; explicit s_waitcnt vmcnt(16) keeps 16
// loads in flight while the previous 16-k chunk computes. Single-wave block
// => LDS is wave-private, no barrier needed in the pipeline.
__global__ void __launch_bounds__(64)
k_proj5(const float* __restrict__ WiT, const float* __restrict__ WsT,
        const float* __restrict__ Wbil, const float* __restrict__ bi,
        const float* __restrict__ bs,
        const float* __restrict__ cH, const float* __restrict__ cC,
        float* __restrict__ cPI, float* __restrict__ cPS, float* __restrict__ cU,
        int d, int P){
  __shared__ float As[8*512];       // [m][k], 16 KB
  __shared__ float Wb[2][16*64];    // [buf][k16][lane], 8 KB
  const int t = threadIdx.x;
  const int g = blockIdx.x;
  const int m0 = blockIdx.y*8;
  const int Mtot = NB*P;
  const int nm = min(8, Mtot-m0);

  int kind, j;
  if (g < 40){ kind=0; j = g*64 + t; }
  else if (g < 80){ kind=1; j = (g-40)*64 + t; }
  else { kind=2; j = (g-80)*64 + t; }

  int cells[8];
  #pragma unroll
  for (int m=0;m<8;m++){
    int mg = m0 + (m < nm ? m : 0);   // clamp dead rows to a valid cell
    int b = mg/P, i = mg%P;
    cells[m] = b*NCELL + coff(d) + i;
  }

  float acc[8];
  #pragma unroll
  for (int m=0;m<8;m++) acc[m] = 0.f;

  const int npass = (kind==2) ? 2 : 1;
  for (int pass=0; pass<npass; pass++){
    // stage 8 rows x 512 floats, coalesced float4 reads -> LDS [m][k]
    const float* __restrict__ srcbase = (kind==2 && pass==1) ? cC : cH;
    if (pass) __syncthreads();
    #pragma unroll
    for (int m=0;m<8;m++){
      const float4* src = (const float4*)(srcbase + (size_t)cells[m]*H);
      float4 v0 = src[t];
      float4 v1 = src[t+64];
      ((float4*)&As[m*512])[t]    = v0;
      ((float4*)&As[m*512])[t+64] = v1;
    }
    __syncthreads();   // also drains vmcnt to 0 before the DMA pipeline

    const float* __restrict__ Wp; size_t ldw;
    if (kind==0){ Wp = WiT;  ldw = H5; }
    else if (kind==1){ Wp = WsT;  ldw = H5; }
    else { Wp = Wbil + (size_t)pass*H*H2; ldw = H2; }
    const float* gcol = Wp + j;   // per-lane column pointer; row k at +k*ldw

    // prologue: chunk 0 in flight
    #pragma unroll
    for (int u=0;u<16;u++)
      dma_row(gcol + (size_t)u*ldw, &Wb[0][u*64]);

    for (int c=0; c<32; c++){
      const float* cur = Wb[c&1];
      if (c < 31){
        const int k1 = (c+1)*16;
        float* nxt = Wb[(c+1)&1];
        #pragma unroll
        for (int u=0;u<16;u++)
          dma_row(gcol + (size_t)(k1+u)*ldw, &nxt[u*64]);
        asm volatile("s_waitcnt vmcnt(16)" ::: "memory");  // chunk c complete
      } else {
        asm volatile("s_waitcnt vmcnt(0)" ::: "memory");
      }
      const int k0 = c*16;
      #pragma unroll
      for (int u=0;u<16;u+=4){
        float w0 = cur[(u+0)*64 + t];
        float w1 = cur[(u+1)*64 + t];
        float w2 = cur[(u+2)*64 + t];
        float w3 = cur[(u+3)*64 + t];
        #pragma unroll
        for (int m=0;m<8;m++){
          float4 a = *(const float4*)&As[m*512 + k0 + u];
          acc[m] = fmaf(a.x, w0, acc[m]);
          acc[m] = fmaf(a.y, w1, acc[m]);
          acc[m] = fmaf(a.z, w2, acc[m]);
          acc[m] = fmaf(a.w, w3, acc[m]);
        }
      }
    }
  }

  float bias = 0.f;
  if (kind==0) bias = bi[j] + ((j>=H && j<3*H)?1.f:0.f);   // ins_bias on [H,3H)
  else if (kind==1) bias = bs[j];

  for (int m=0;m<nm;m++){
    int cell = cells[m];
    if (kind==0)      cPI[(size_t)cell*H5 + j] = acc[m]+bias;
    else if (kind==1) cPS[(size_t)cell*H5 + j] = acc[m]+bias;
    else              cU [(size_t)cell*H2 + j] = acc[m];
  }
}

// ---- combine diagonal L: one block per (b,left) span of length L+1
__global__ void k_combine(const float* __restrict__ cPI, const float* __restrict__ cPS,
                          const float* __restrict__ cU,
                          float* __restrict__ cH, float* __restrict__ cC, float* __restrict__ cS,
                          int L, int P){
  const int t = threadIdx.x;
  const int b = blockIdx.x / P;
  const int left = blockIdx.x % P;
  __shared__ float compat_s[32];
  __shared__ float wts_s[32];
  __shared__ float S_s;
  const int lane = t & 63;
  const int wv = t >> 6;
  // phase 1: compat_k = U[lcell] . [H;C][rcell] + lS + rS, waves parallel over k
  for (int k=wv; k<L; k+=4){
    int lc = b*NCELL + coff(k) + left;
    int rc = b*NCELL + coff(L-1-k) + left+k+1;
    const float* U  = cU + (size_t)lc*H2;
    const float* Hr = cH + (size_t)rc*H;
    const float* Cr = cC + (size_t)rc*H;
    float p = 0.f;
    for (int i=lane; i<H; i+=64)
      p += U[i]*Hr[i] + U[H+i]*Cr[i];
    #pragma unroll
    for (int off=32; off>0; off>>=1) p += __shfl_down(p, off);
    if (lane==0) compat_s[k] = p + cS[lc] + cS[rc];
  }
  __syncthreads();
  // phase 2: softmax over k (L<=23, serial on thread 0)
  if (t==0){
    float mx = -1e30f;
    for (int k=0;k<L;k++) mx = fmaxf(mx, compat_s[k]);
    float den = 0.f;
    for (int k=0;k<L;k++){ float e = __expf(compat_s[k]-mx); wts_s[k]=e; den+=e; }
    float inv = 1.f/den, S = 0.f;
    for (int k=0;k<L;k++){ wts_s[k]*=inv; S += wts_s[k]*compat_s[k]; }
    S_s = S;
  }
  __syncthreads();
  // phase 3: gates + weighted accumulate; thread t handles dims t and t+256
  float aH0=0.f, aH1=0.f, aC0=0.f, aC1=0.f;
  const int d0 = t, d1 = t+256;
  for (int k=0;k<L;k++){
    float wk = wts_s[k];
    int lc = b*NCELL + coff(k) + left;
    int rc = b*NCELL + coff(L-1-k) + left+k+1;
    const float* PI  = cPI + (size_t)lc*H5;
    const float* PS  = cPS + (size_t)rc*H5;
    const float* lCp = cC + (size_t)lc*H;
    const float* rCp = cC + (size_t)rc*H;
    {
      float p0 = PI[d0]     + PS[d0];
      float p1 = PI[H+d0]   + PS[H+d0];
      float p2 = PI[2*H+d0] + PS[2*H+d0];
      float p3 = PI[3*H+d0] + PS[3*H+d0];
      float p4 = PI[4*H+d0] + PS[4*H+d0];
      float mem = sigm(p1)*lCp[d0] + sigm(p2)*rCp[d0] + sigm(p0)*ftanh(p3);
      float h = sigm(p4)*ftanh(mem);
      aH0 += wk*h; aC0 += wk*mem;
    }
    {
      float p0 = PI[d1]     + PS[d1];
      float p1 = PI[H+d1]   + PS[H+d1];
      float p2 = PI[2*H+d1] + PS[2*H+d1];
      float p3 = PI[3*H+d1] + PS[3*H+d1];
      float p4 = PI[4*H+d1] + PS[4*H+d1];
      float mem = sigm(p1)*lCp[d1] + sigm(p2)*rCp[d1] + sigm(p0)*ftanh(p3);
      float h = sigm(p4)*ftanh(mem);
      aH1 += wk*h; aC1 += wk*mem;
    }
  }
  int nc = b*NCELL + coff(L) + left;
  cH[(size_t)nc*H + d0] = aH0; cH[(size_t)nc*H + d1] = aH1;
  cC[(size_t)nc*H + d0] = aC0; cC[(size_t)nc*H + d1] = aC1;
  if (t==0) cS[nc] = S_s;
}

// ---- root output: concat(H, C) of cell (0, n-1)
__global__ void k_out(const float* __restrict__ cH, const float* __restrict__ cC,
                      float* __restrict__ out){
  int tid = blockIdx.x*256+threadIdx.x;
  if (tid >= NB*H2) return;
  int b = tid>>10, d = tid&1023;
  int cell = b*NCELL + 299;   // coff(23)+0
  out[tid] = (d<H) ? cH[(size_t)cell*H + d] : cC[(size_t)cell*H + (d-H)];
}

extern "C" void kernel_launch(void* const* d_in, const int* in_sizes, int n_in,
                              void* d_out, int out_size, void* d_ws, size_t ws_size,
                              hipStream_t stream){
  const float* seqt = (const float*)d_in[0];
  const float* Wi   = (const float*)d_in[1];
  const float* bi   = (const float*)d_in[2];
  const float* Ws   = (const float*)d_in[3];
  const float* bs   = (const float*)d_in[4];
  const float* Wbil = (const float*)d_in[5];
  float* out = (float*)d_out;

  float* p = (ws_size >= NEED_BYTES && g_buf == nullptr) ? (float*)d_ws : g_buf;
  float* WiT = p; p += (size_t)H*H5;          // 512*2560
  float* WsT = p; p += (size_t)H*H5;
  float* cH  = p; p += (size_t)NB*NCELL*H;
  float* cC  = p; p += (size_t)NB*NCELL*H;
  float* cS  = p; p += (size_t)NB*NCELL;
  float* cPI = p; p += (size_t)NB*NCELL*H5;
  float* cPS = p; p += (size_t)NB*NCELL*H5;
  float* cU  = p; p += (size_t)NB*NCELL*H2;

  k_transpose<<<dim3(16,80,2), dim3(32,8), 0, stream>>>(Wi, Ws, WiT, WsT);
  k_leaf<<<(NB*NW*H+255)/256, 256, 0, stream>>>(seqt, cH, cC, cS);
  k_proj5<<<dim3(96, (NB*NW+7)/8), 64, 0, stream>>>(
      WiT, WsT, Wbil, bi, bs, cH, cC, cPI, cPS, cU, 0, NW);
  for (int L=1; L<NW; L++){
    int P = NW - L;
    k_combine<<<NB*P, 256, 0, stream>>>(cPI, cPS, cU, cH, cC, cS, L, P);
    if (L < NW-1)
      k_proj5<<<dim3(96, (NB*P+7)/8), 64, 0, stream>>>(
          WiT, WsT, Wbil, bi, bs, cH, cC, cPI, cPS, cU, L, P);
  }
  k_out<<<16, 256, 0, stream>>>(cH, cC, out);
}

// Round 7
// 2208.446 us; speedup vs baseline: 1.0468x; 1.0468x over previous
//
#include <hip/hip_runtime.h>
#include <math.h>

#define NB 4
#define NW 24
#define H 512
#define H2 1024
#define H5 2560
#define NCELL 300   // n*(n+1)/2 valid cells per batch

// total workspace floats needed
#define NEED_FLOATS (2u*H*H5 + 2u*NB*NCELL*H + NB*NCELL + 2u*NB*NCELL*H5 + NB*NCELL*H2)
#define NEED_BYTES  ((size_t)NEED_FLOATS * 4u)

// Private fallback workspace: allocated ONCE at library load (outside
// kernel_launch, so graph capture never sees the hipMalloc). d_ws proved too
// small in round 1 (44.9MB layout corrupted adjacent harness allocations).
static float* g_buf = nullptr;
__attribute__((constructor)) static void dio_alloc_ws(){
  (void)hipMalloc((void**)&g_buf, NEED_BYTES + (1u<<20));
}

__device__ __forceinline__ int coff(int l){ return l*NW - (l*(l-1))/2; }
__device__ __forceinline__ float sigm(float x){ return 1.f/(1.f+__expf(-x)); }
__device__ __forceinline__ float ftanh(float x){ return 1.f - 2.f/(__expf(2.f*x)+1.f); }

// ---- transpose Wi [2560,512] -> WiT [512,2560] (and Ws) for coalesced proj reads
__global__ void k_transpose(const float* __restrict__ Wi, const float* __restrict__ Ws,
                            float* __restrict__ WiT, float* __restrict__ WsT){
  const float* in  = blockIdx.z ? Ws  : Wi;
  float*       out = blockIdx.z ? WsT : WiT;
  __shared__ float tile[32][33];
  int tr = blockIdx.y*32, tc = blockIdx.x*32;
  int tx = threadIdx.x, ty = threadIdx.y;
  #pragma unroll
  for (int i=0;i<32;i+=8)
    tile[ty+i][tx] = in[(size_t)(tr+ty+i)*H + tc+tx];
  __syncthreads();
  #pragma unroll
  for (int i=0;i<32;i+=8)
    out[(size_t)(tc+ty+i)*H5 + tr+tx] = tile[tx][ty+i];
}

// ---- leaves: cell (i,0): H = seq[i,:512], C = seq[i,512:], S = 0
__global__ void k_leaf(const float* __restrict__ seqt, float* __restrict__ cH,
                       float* __restrict__ cC, float* __restrict__ cS){
  int tid = blockIdx.x*256 + threadIdx.x;
  if (tid >= NB*NW*H) return;
  int b = tid/(NW*H); int r = tid%(NW*H); int i = r/H; int d = r%H;
  int cell = b*NCELL + i;                 // coff(0)==0
  cH[(size_t)cell*H + d] = seqt[(size_t)(b*NW+i)*H2 + d];
  cC[(size_t)cell*H + d] = seqt[(size_t)(b*NW+i)*H2 + H + d];
  if (d==0) cS[cell] = 0.f;
}

// 16-k chunk of FMAs: acc[m] += As[m][k0..k0+15] * w[0..15]
__device__ __forceinline__ void chunk_fma(const float* __restrict__ As,
                                          float acc[8], int k0, const float w[16]){
  #pragma unroll
  for (int u=0;u<16;u+=4){
    float4 a[8];
    #pragma unroll
    for (int m=0;m<8;m++)
      a[m] = *(const float4*)&As[m*512 + k0 + u];
    #pragma unroll
    for (int m=0;m<8;m++){
      acc[m] = fmaf(a[m].x, w[u+0], acc[m]);
      acc[m] = fmaf(a[m].y, w[u+1], acc[m]);
      acc[m] = fmaf(a[m].z, w[u+2], acc[m]);
      acc[m] = fmaf(a[m].w, w[u+3], acc[m]);
    }
  }
}

// K=512 pass with double-buffered weight prefetch. Rounds 4-6 all plateaued
// at ~400cy/load (fully serialized): __launch_bounds__(64) let the compiler
// cap VGPRs at ~72, starving the prefetch. With min-waves=1 (512 VGPR
// budget) the 16 independent loads can actually stay in flight.
__device__ __forceinline__ void pass512(const float* __restrict__ Wp, int ldw,
                                        const float* __restrict__ As, float acc[8]){
  float wA[16], wB[16];
  #pragma unroll
  for (int u=0;u<16;u++) wA[u] = Wp[(size_t)u*ldw];
  for (int k0=0; k0<512; k0+=32){
    #pragma unroll
    for (int u=0;u<16;u++) wB[u] = Wp[(size_t)(k0+16+u)*ldw];
    chunk_fma(As, acc, k0, wA);
    const float* Wn = Wp + (size_t)((k0+32)&511)*ldw;   // wraps to dummy chunk 0 at end
    #pragma unroll
    for (int u=0;u<16;u++) wA[u] = Wn[(size_t)u*ldw];
    chunk_fma(As, acc, k0+16, wB);
  }
}

// ---- per-cell projections for diagonal d:
//   PI = H@Wi^T + bi + ins_bias ; PS = H@Ws^T + bs ; U = [H,C]^T Wbil
// Block = 1 wave; thread owns column j = group*64+t for 8 m-rows.
// grid.x = 96 j-groups (0-39: PI, 40-79: PS, 80-95: U), grid.y = m-tiles of 8.
__global__ void __launch_bounds__(64, 1)
k_proj6(const float* __restrict__ WiT, const float* __restrict__ WsT,
        const float* __restrict__ Wbil, const float* __restrict__ bi,
        const float* __restrict__ bs,
        const float* __restrict__ cH, const float* __restrict__ cC,
        float* __restrict__ cPI, float* __restrict__ cPS, float* __restrict__ cU,
        int d, int P){
  __shared__ float As[8*512];   // [m][k], 16 KB
  const int t = threadIdx.x;
  const int g = blockIdx.x;
  const int m0 = blockIdx.y*8;
  const int Mtot = NB*P;
  const int nm = min(8, Mtot-m0);

  int kind, j;
  if (g < 40){ kind=0; j = g*64 + t; }
  else if (g < 80){ kind=1; j = (g-40)*64 + t; }
  else { kind=2; j = (g-80)*64 + t; }

  int cells[8];
  #pragma unroll
  for (int m=0;m<8;m++){
    int mg = m0 + (m < nm ? m : 0);   // clamp dead rows to a valid cell
    int b = mg/P, i = mg%P;
    cells[m] = b*NCELL + coff(d) + i;
  }

  float acc[8];
  #pragma unroll
  for (int m=0;m<8;m++) acc[m] = 0.f;

  const int npass = (kind==2) ? 2 : 1;
  for (int pass=0; pass<npass; pass++){
    // stage 8 rows x 512 floats, coalesced float4 reads -> LDS [m][k]
    const float* __restrict__ srcbase = (kind==2 && pass==1) ? cC : cH;
    if (pass) __syncthreads();
    #pragma unroll
    for (int m=0;m<8;m++){
      const float4* src = (const float4*)(srcbase + (size_t)cells[m]*H);
      float4 v0 = src[t];
      float4 v1 = src[t+64];
      ((float4*)&As[m*512])[t]    = v0;
      ((float4*)&As[m*512])[t+64] = v1;
    }
    __syncthreads();

    const float* __restrict__ Wp; int ldw;
    if (kind==0){ Wp = WiT;  ldw = H5; }
    else if (kind==1){ Wp = WsT;  ldw = H5; }
    else { Wp = Wbil + (size_t)pass*H*H2; ldw = H2; }
    Wp += j;

    pass512(Wp, ldw, As, acc);
  }

  float bias = 0.f;
  if (kind==0) bias = bi[j] + ((j>=H && j<3*H)?1.f:0.f);   // ins_bias on [H,3H)
  else if (kind==1) bias = bs[j];

  for (int m=0;m<nm;m++){
    int cell = cells[m];
    if (kind==0)      cPI[(size_t)cell*H5 + j] = acc[m]+bias;
    else if (kind==1) cPS[(size_t)cell*H5 + j] = acc[m]+bias;
    else              cU [(size_t)cell*H2 + j] = acc[m];
  }
}

// ---- combine diagonal L: one block per (b,left) span of length L+1
__global__ void k_combine(const float* __restrict__ cPI, const float* __restrict__ cPS,
                          const float* __restrict__ cU,
                          float* __restrict__ cH, float* __restrict__ cC, float* __restrict__ cS,
                          int L, int P){
  const int t = threadIdx.x;
  const int b = blockIdx.x / P;
  const int left = blockIdx.x % P;
  __shared__ float compat_s[32];
  __shared__ float wts_s[32];
  __shared__ float S_s;
  const int lane = t & 63;
  const int wv = t >> 6;
  // phase 1: compat_k = U[lcell] . [H;C][rcell] + lS + rS, waves parallel over k
  for (int k=wv; k<L; k+=4){
    int lc = b*NCELL + coff(k) + left;
    int rc = b*NCELL + coff(L-1-k) + left+k+1;
    const float* U  = cU + (size_t)lc*H2;
    const float* Hr = cH + (size_t)rc*H;
    const float* Cr = cC + (size_t)rc*H;
    float p = 0.f;
    for (int i=lane; i<H; i+=64)
      p += U[i]*Hr[i] + U[H+i]*Cr[i];
    #pragma unroll
    for (int off=32; off>0; off>>=1) p += __shfl_down(p, off);
    if (lane==0) compat_s[k] = p + cS[lc] + cS[rc];
  }
  __syncthreads();
  // phase 2: softmax over k (L<=23, serial on thread 0)
  if (t==0){
    float mx = -1e30f;
    for (int k=0;k<L;k++) mx = fmaxf(mx, compat_s[k]);
    float den = 0.f;
    for (int k=0;k<L;k++){ float e = __expf(compat_s[k]-mx); wts_s[k]=e; den+=e; }
    float inv = 1.f/den, S = 0.f;
    for (int k=0;k<L;k++){ wts_s[k]*=inv; S += wts_s[k]*compat_s[k]; }
    S_s = S;
  }
  __syncthreads();
  // phase 3: gates + weighted accumulate; thread t handles dims t and t+256
  float aH0=0.f, aH1=0.f, aC0=0.f, aC1=0.f;
  const int d0 = t, d1 = t+256;
  for (int k=0;k<L;k++){
    float wk = wts_s[k];
    int lc = b*NCELL + coff(k) + left;
    int rc = b*NCELL + coff(L-1-k) + left+k+1;
    const float* PI  = cPI + (size_t)lc*H5;
    const float* PS  = cPS + (size_t)rc*H5;
    const float* lCp = cC + (size_t)lc*H;
    const float* rCp = cC + (size_t)rc*H;
    {
      float p0 = PI[d0]     + PS[d0];
      float p1 = PI[H+d0]   + PS[H+d0];
      float p2 = PI[2*H+d0] + PS[2*H+d0];
      float p3 = PI[3*H+d0] + PS[3*H+d0];
      float p4 = PI[4*H+d0] + PS[4*H+d0];
      float mem = sigm(p1)*lCp[d0] + sigm(p2)*rCp[d0] + sigm(p0)*ftanh(p3);
      float h = sigm(p4)*ftanh(mem);
      aH0 += wk*h; aC0 += wk*mem;
    }
    {
      float p0 = PI[d1]     + PS[d1];
      float p1 = PI[H+d1]   + PS[H+d1];
      float p2 = PI[2*H+d1] + PS[2*H+d1];
      float p3 = PI[3*H+d1] + PS[3*H+d1];
      float p4 = PI[4*H+d1] + PS[4*H+d1];
      float mem = sigm(p1)*lCp[d1] + sigm(p2)*rCp[d1] + sigm(p0)*ftanh(p3);
      float h = sigm(p4)*ftanh(mem);
      aH1 += wk*h; aC1 += wk*mem;
    }
  }
  int nc = b*NCELL + coff(L) + left;
  cH[(size_t)nc*H + d0] = aH0; cH[(size_t)nc*H + d1] = aH1;
  cC[(size_t)nc*H + d0] = aC0; cC[(size_t)nc*H + d1] = aC1;
  if (t==0) cS[nc] = S_s;
}

// ---- root output: concat(H, C) of cell (0, n-1)
__global__ void k_out(const float* __restrict__ cH, const float* __restrict__ cC,
                      float* __restrict__ out){
  int tid = blockIdx.x*256+threadIdx.x;
  if (tid >= NB*H2) return;
  int b = tid>>10, d = tid&1023;
  int cell = b*NCELL + 299;   // coff(23)+0
  out[tid] = (d<H) ? cH[(size_t)cell*H + d] : cC[(size_t)cell*H + (d-H)];
}

extern "C" void kernel_launch(void* const* d_in, const int* in_sizes, int n_in,
                              void* d_out, int out_size, void* d_ws, size_t ws_size,
                              hipStream_t stream){
  const float* seqt = (const float*)d_in[0];
  const float* Wi   = (const float*)d_in[1];
  const float* bi   = (const float*)d_in[2];
  const float* Ws   = (const float*)d_in[3];
  const float* bs   = (const float*)d_in[4];
  const float* Wbil = (const float*)d_in[5];
  float* out = (float*)d_out;

  float* p = (ws_size >= NEED_BYTES && g_buf == nullptr) ? (float*)d_ws : g_buf;
  float* WiT = p; p += (size_t)H*H5;          // 512*2560
  float* WsT = p; p += (size_t)H*H5;
  float* cH  = p; p += (size_t)NB*NCELL*H;
  float* cC  = p; p += (size_t)NB*NCELL*H;
  float* cS  = p; p += (size_t)NB*NCELL;
  float* cPI = p; p += (size_t)NB*NCELL*H5;
  float* cPS = p; p += (size_t)NB*NCELL*H5;
  float* cU  = p; p += (size_t)NB*NCELL*H2;

  k_transpose<<<dim3(16,80,2), dim3(32,8), 0, stream>>>(Wi, Ws, WiT, WsT);
  k_leaf<<<(NB*NW*H+255)/256, 256, 0, stream>>>(seqt, cH, cC, cS);
  k_proj6<<<dim3(96, (NB*NW+7)/8), 64, 0, stream>>>(
      WiT, WsT, Wbil, bi, bs, cH, cC, cPI, cPS, cU, 0, NW);
  for (int L=1; L<NW; L++){
    int P = NW - L;
    k_combine<<<NB*P, 256, 0, stream>>>(cPI, cPS, cU, cH, cC, cS, L, P);
    if (L < NW-1)
      k_proj6<<<dim3(96, (NB*P+7)/8), 64, 0, stream>>>(
          WiT, WsT, Wbil, bi, bs, cH, cC, cPI, cPS, cU, L, P);
  }
  k_out<<<16, 256, 0, stream>>>(cH, cC, out);
}

// Round 8
// 1210.708 us; speedup vs baseline: 1.9094x; 1.8241x over previous
//
#include <hip/hip_runtime.h>
#include <math.h>

#define NB 4
#define NW 24
#define H 512
#define H2 1024
#define H5 2560
#define NCELL 300   // n*(n+1)/2 valid cells per batch

// workspace floats: WbilT + chartH + chartC + chartS + PI + PS + U
#define NEED_FLOATS ((size_t)H2*H2 + 2u*NB*NCELL*H + NB*NCELL + 2u*NB*NCELL*H5 + NB*NCELL*H2)
#define NEED_BYTES  ((size_t)NEED_FLOATS * 4u)

// Private fallback workspace: allocated ONCE at library load (outside
// kernel_launch, so graph capture never sees the hipMalloc). d_ws proved too
// small in round 1 (44.9MB layout corrupted adjacent harness allocations).
static float* g_buf = nullptr;
__attribute__((constructor)) static void dio_alloc_ws(){
  (void)hipMalloc((void**)&g_buf, NEED_BYTES + (1u<<20));
}

__device__ __forceinline__ int coff(int l){ return l*NW - (l*(l-1))/2; }
__device__ __forceinline__ float sigm(float x){ return 1.f/(1.f+__expf(-x)); }
__device__ __forceinline__ float ftanh(float x){ return 1.f - 2.f/(__expf(2.f*x)+1.f); }

// ---- transpose Wbil [1024,1024] -> WbilT (U's contraction is over Wbil's
// FIRST index; Wi/Ws need no transpose: their k-index is already contiguous)
__global__ void k_transpose_bil(const float* __restrict__ Wbil, float* __restrict__ WbilT){
  __shared__ float tile[32][33];
  int tr = blockIdx.y*32, tc = blockIdx.x*32;
  int tx = threadIdx.x, ty = threadIdx.y;
  #pragma unroll
  for (int i=0;i<32;i+=8)
    tile[ty+i][tx] = Wbil[(size_t)(tr+ty+i)*H2 + tc+tx];
  __syncthreads();
  #pragma unroll
  for (int i=0;i<32;i+=8)
    WbilT[(size_t)(tc+ty+i)*H2 + tr+tx] = tile[tx][ty+i];
}

// ---- leaves: cell (i,0): H = seq[i,:512], C = seq[i,512:], S = 0
__global__ void k_leaf(const float* __restrict__ seqt, float* __restrict__ cH,
                       float* __restrict__ cC, float* __restrict__ cS){
  int tid = blockIdx.x*256 + threadIdx.x;
  if (tid >= NB*NW*H) return;
  int b = tid/(NW*H); int r = tid%(NW*H); int i = r/H; int d = r%H;
  int cell = b*NCELL + i;                 // coff(0)==0
  cH[(size_t)cell*H + d] = seqt[(size_t)(b*NW+i)*H2 + d];
  cC[(size_t)cell*H + d] = seqt[(size_t)(b*NW+i)*H2 + H + d];
  if (d==0) cS[cell] = 0.f;
}

// ---- per-cell projections for diagonal d:
//   PI = H@Wi^T + bi + ins_bias ; PS = H@Ws^T + bs ; U = [H,C]^T Wbil
// Rounds 4-7 lesson: column-strided weight reads = 512 serialized dword
// loads/wave (~375cy each = 80us) and the compiler refuses to pipeline them.
// Fix is layout, not scheduling: read weights ALONG k (contiguous in the
// original Wi/Ws [j][k] storage) as dwordx4 -> 32 loads per K=512 pass.
// Block = 256 thr (4 waves x 16 j); lane = (jj = lane&15, kk = lane>>4)
// owns column j for k-quarter kk; 4-way k-split reduced by shfl_xor(16/32).
// grid.x = 96 j-groups of 64 (0-39: PI, 40-79: PS, 80-95: U), grid.y = m/8.
__global__ void __launch_bounds__(256)
k_proj7(const float* __restrict__ Wi, const float* __restrict__ Ws,
        const float* __restrict__ WbilT, const float* __restrict__ bi,
        const float* __restrict__ bs,
        const float* __restrict__ cH, const float* __restrict__ cC,
        float* __restrict__ cPI, float* __restrict__ cPS, float* __restrict__ cU,
        int d, int P){
  __shared__ float As[8*512];   // [m][k], 16 KB
  const int t = threadIdx.x;
  const int g = blockIdx.x;
  const int m0 = blockIdx.y*8;
  const int Mtot = NB*P;
  const int nm = min(8, Mtot-m0);

  int kind, j0;
  if (g < 40){ kind=0; j0 = g*64; }
  else if (g < 80){ kind=1; j0 = (g-40)*64; }
  else { kind=2; j0 = (g-80)*64; }

  const int wave = t>>6, lane = t&63;
  const int jj = lane & 15, kk = lane >> 4;
  const int j = j0 + wave*16 + jj;

  int cells[8];
  #pragma unroll
  for (int m=0;m<8;m++){
    int mg = m0 + (m < nm ? m : 0);   // clamp dead rows to a valid cell
    int b = mg/P, i = mg%P;
    cells[m] = b*NCELL + coff(d) + i;
  }

  float acc[8];
  #pragma unroll
  for (int m=0;m<8;m++) acc[m] = 0.f;

  const int npass = (kind==2) ? 2 : 1;
  for (int pass=0; pass<npass; pass++){
    // stage 8 rows x 512 floats -> LDS [m][k]; 1024 float4s over 256 threads
    const float* __restrict__ srcbase = (kind==2 && pass==1) ? cC : cH;
    if (pass) __syncthreads();
    #pragma unroll
    for (int it=0; it<4; it++){
      int idx = t + it*256;
      int m = idx>>7, k4 = idx&127;
      ((float4*)As)[idx] = ((const float4*)(srcbase + (size_t)cells[m]*H))[k4];
    }
    __syncthreads();

    // this lane's contiguous k-run base (steps of 16 floats per chunk)
    const float* __restrict__ gk;
    if (kind==0)      gk = Wi    + (size_t)j*H  + kk*4;
    else if (kind==1) gk = Ws    + (size_t)j*H  + kk*4;
    else              gk = WbilT + (size_t)j*H2 + (size_t)pass*H + kk*4;

    float4 wc = *(const float4*)gk;
    #pragma unroll
    for (int c=0; c<31; c++){
      float4 wn = *(const float4*)(gk + (c+1)*16);
      const int kb = c*16 + kk*4;
      #pragma unroll
      for (int m=0;m<8;m++){
        float4 a = *(const float4*)&As[m*512 + kb];
        acc[m] = fmaf(a.x, wc.x, acc[m]);
        acc[m] = fmaf(a.y, wc.y, acc[m]);
        acc[m] = fmaf(a.z, wc.z, acc[m]);
        acc[m] = fmaf(a.w, wc.w, acc[m]);
      }
      wc = wn;
    }
    {
      const int kb = 31*16 + kk*4;
      #pragma unroll
      for (int m=0;m<8;m++){
        float4 a = *(const float4*)&As[m*512 + kb];
        acc[m] = fmaf(a.x, wc.x, acc[m]);
        acc[m] = fmaf(a.y, wc.y, acc[m]);
        acc[m] = fmaf(a.z, wc.z, acc[m]);
        acc[m] = fmaf(a.w, wc.w, acc[m]);
      }
    }
  }

  // fold the 4-way k-split (lanes differing in bits 4,5)
  #pragma unroll
  for (int m=0;m<8;m++){
    acc[m] += __shfl_xor(acc[m], 16);
    acc[m] += __shfl_xor(acc[m], 32);
  }

  if (kk == 0){
    float bias = 0.f;
    if (kind==0) bias = bi[j] + ((j>=H && j<3*H)?1.f:0.f);   // ins_bias on [H,3H)
    else if (kind==1) bias = bs[j];
    for (int m=0;m<nm;m++){
      int cell = cells[m];
      if (kind==0)      cPI[(size_t)cell*H5 + j] = acc[m]+bias;
      else if (kind==1) cPS[(size_t)cell*H5 + j] = acc[m]+bias;
      else              cU [(size_t)cell*H2 + j] = acc[m];
    }
  }
}

// ---- combine diagonal L: one block per (b,left) span of length L+1
__global__ void k_combine(const float* __restrict__ cPI, const float* __restrict__ cPS,
                          const float* __restrict__ cU,
                          float* __restrict__ cH, float* __restrict__ cC, float* __restrict__ cS,
                          int L, int P){
  const int t = threadIdx.x;
  const int b = blockIdx.x / P;
  const int left = blockIdx.x % P;
  __shared__ float compat_s[32];
  __shared__ float wts_s[32];
  __shared__ float S_s;
  const int lane = t & 63;
  const int wv = t >> 6;
  // phase 1: compat_k = U[lcell] . [H;C][rcell] + lS + rS, waves parallel over k
  for (int k=wv; k<L; k+=4){
    int lc = b*NCELL + coff(k) + left;
    int rc = b*NCELL + coff(L-1-k) + left+k+1;
    const float* U  = cU + (size_t)lc*H2;
    const float* Hr = cH + (size_t)rc*H;
    const float* Cr = cC + (size_t)rc*H;
    float p = 0.f;
    for (int i=lane; i<H; i+=64)
      p += U[i]*Hr[i] + U[H+i]*Cr[i];
    #pragma unroll
    for (int off=32; off>0; off>>=1) p += __shfl_down(p, off);
    if (lane==0) compat_s[k] = p + cS[lc] + cS[rc];
  }
  __syncthreads();
  // phase 2: softmax over k (L<=23, serial on thread 0)
  if (t==0){
    float mx = -1e30f;
    for (int k=0;k<L;k++) mx = fmaxf(mx, compat_s[k]);
    float den = 0.f;
    for (int k=0;k<L;k++){ float e = __expf(compat_s[k]-mx); wts_s[k]=e; den+=e; }
    float inv = 1.f/den, S = 0.f;
    for (int k=0;k<L;k++){ wts_s[k]*=inv; S += wts_s[k]*compat_s[k]; }
    S_s = S;
  }
  __syncthreads();
  // phase 3: gates + weighted accumulate; thread t handles dims t and t+256
  float aH0=0.f, aH1=0.f, aC0=0.f, aC1=0.f;
  const int d0 = t, d1 = t+256;
  for (int k=0;k<L;k++){
    float wk = wts_s[k];
    int lc = b*NCELL + coff(k) + left;
    int rc = b*NCELL + coff(L-1-k) + left+k+1;
    const float* PI  = cPI + (size_t)lc*H5;
    const float* PS  = cPS + (size_t)rc*H5;
    const float* lCp = cC + (size_t)lc*H;
    const float* rCp = cC + (size_t)rc*H;
    {
      float p0 = PI[d0]     + PS[d0];
      float p1 = PI[H+d0]   + PS[H+d0];
      float p2 = PI[2*H+d0] + PS[2*H+d0];
      float p3 = PI[3*H+d0] + PS[3*H+d0];
      float p4 = PI[4*H+d0] + PS[4*H+d0];
      float mem = sigm(p1)*lCp[d0] + sigm(p2)*rCp[d0] + sigm(p0)*ftanh(p3);
      float h = sigm(p4)*ftanh(mem);
      aH0 += wk*h; aC0 += wk*mem;
    }
    {
      float p0 = PI[d1]     + PS[d1];
      float p1 = PI[H+d1]   + PS[H+d1];
      float p2 = PI[2*H+d1] + PS[2*H+d1];
      float p3 = PI[3*H+d1] + PS[3*H+d1];
      float p4 = PI[4*H+d1] + PS[4*H+d1];
      float mem = sigm(p1)*lCp[d1] + sigm(p2)*rCp[d1] + sigm(p0)*ftanh(p3);
      float h = sigm(p4)*ftanh(mem);
      aH1 += wk*h; aC1 += wk*mem;
    }
  }
  int nc = b*NCELL + coff(L) + left;
  cH[(size_t)nc*H + d0] = aH0; cH[(size_t)nc*H + d1] = aH1;
  cC[(size_t)nc*H + d0] = aC0; cC[(size_t)nc*H + d1] = aC1;
  if (t==0) cS[nc] = S_s;
}

// ---- root output: concat(H, C) of cell (0, n-1)
__global__ void k_out(const float* __restrict__ cH, const float* __restrict__ cC,
                      float* __restrict__ out){
  int tid = blockIdx.x*256+threadIdx.x;
  if (tid >= NB*H2) return;
  int b = tid>>10, d = tid&1023;
  int cell = b*NCELL + 299;   // coff(23)+0
  out[tid] = (d<H) ? cH[(size_t)cell*H + d] : cC[(size_t)cell*H + (d-H)];
}

extern "C" void kernel_launch(void* const* d_in, const int* in_sizes, int n_in,
                              void* d_out, int out_size, void* d_ws, size_t ws_size,
                              hipStream_t stream){
  const float* seqt = (const float*)d_in[0];
  const float* Wi   = (const float*)d_in[1];
  const float* bi   = (const float*)d_in[2];
  const float* Ws   = (const float*)d_in[3];
  const float* bs   = (const float*)d_in[4];
  const float* Wbil = (const float*)d_in[5];
  float* out = (float*)d_out;

  float* p = (ws_size >= NEED_BYTES && g_buf == nullptr) ? (float*)d_ws : g_buf;
  float* WbilT = p; p += (size_t)H2*H2;
  float* cH  = p; p += (size_t)NB*NCELL*H;
  float* cC  = p; p += (size_t)NB*NCELL*H;
  float* cS  = p; p += (size_t)NB*NCELL;
  float* cPI = p; p += (size_t)NB*NCELL*H5;
  float* cPS = p; p += (size_t)NB*NCELL*H5;
  float* cU  = p; p += (size_t)NB*NCELL*H2;

  k_transpose_bil<<<dim3(32,32), dim3(32,8), 0, stream>>>(Wbil, WbilT);
  k_leaf<<<(NB*NW*H+255)/256, 256, 0, stream>>>(seqt, cH, cC, cS);
  k_proj7<<<dim3(96, (NB*NW+7)/8), 256, 0, stream>>>(
      Wi, Ws, WbilT, bi, bs, cH, cC, cPI, cPS, cU, 0, NW);
  for (int L=1; L<NW; L++){
    int P = NW - L;
    k_combine<<<NB*P, 256, 0, stream>>>(cPI, cPS, cU, cH, cC, cS, L, P);
    if (L < NW-1)
      k_proj7<<<dim3(96, (NB*P+7)/8), 256, 0, stream>>>(
          Wi, Ws, WbilT, bi, bs, cH, cC, cPI, cPS, cU, L, P);
  }
  k_out<<<16, 256, 0, stream>>>(cH, cC, out);
}

// Round 9
// 1105.641 us; speedup vs baseline: 2.0909x; 1.0950x over previous
//
#include <hip/hip_runtime.h>
#include <math.h>

#define NB 4
#define NW 24
#define H 512
#define H2 1024
#define H5 2560
#define NCELL 300   // n*(n+1)/2 valid cells per batch

// workspace floats: WbilT + chartH + chartC + chartS + PI + PS + U
#define NEED_FLOATS ((size_t)H2*H2 + 2u*NB*NCELL*H + NB*NCELL + 2u*NB*NCELL*H5 + NB*NCELL*H2)
#define NEED_BYTES  ((size_t)NEED_FLOATS * 4u)

// Private fallback workspace: allocated ONCE at library load (outside
// kernel_launch, so graph capture never sees the hipMalloc). d_ws proved too
// small in round 1 (44.9MB layout corrupted adjacent harness allocations).
static float* g_buf = nullptr;
__attribute__((constructor)) static void dio_alloc_ws(){
  (void)hipMalloc((void**)&g_buf, NEED_BYTES + (1u<<20));
}

__device__ __forceinline__ int coff(int l){ return l*NW - (l*(l-1))/2; }
__device__ __forceinline__ float sigm(float x){ return 1.f/(1.f+__expf(-x)); }
__device__ __forceinline__ float ftanh(float x){ return 1.f - 2.f/(__expf(2.f*x)+1.f); }

// ---- transpose Wbil [1024,1024] -> WbilT (U's contraction is over Wbil's
// FIRST index; Wi/Ws need no transpose: their k-index is already contiguous)
__global__ void k_transpose_bil(const float* __restrict__ Wbil, float* __restrict__ WbilT){
  __shared__ float tile[32][33];
  int tr = blockIdx.y*32, tc = blockIdx.x*32;
  int tx = threadIdx.x, ty = threadIdx.y;
  #pragma unroll
  for (int i=0;i<32;i+=8)
    tile[ty+i][tx] = Wbil[(size_t)(tr+ty+i)*H2 + tc+tx];
  __syncthreads();
  #pragma unroll
  for (int i=0;i<32;i+=8)
    WbilT[(size_t)(tc+ty+i)*H2 + tr+tx] = tile[tx][ty+i];
}

// ---- leaves: cell (i,0): H = seq[i,:512], C = seq[i,512:], S = 0
__global__ void k_leaf(const float* __restrict__ seqt, float* __restrict__ cH,
                       float* __restrict__ cC, float* __restrict__ cS){
  int tid = blockIdx.x*256 + threadIdx.x;
  if (tid >= NB*NW*H) return;
  int b = tid/(NW*H); int r = tid%(NW*H); int i = r/H; int d = r%H;
  int cell = b*NCELL + i;                 // coff(0)==0
  cH[(size_t)cell*H + d] = seqt[(size_t)(b*NW+i)*H2 + d];
  cC[(size_t)cell*H + d] = seqt[(size_t)(b*NW+i)*H2 + H + d];
  if (d==0) cS[cell] = 0.f;
}

// ---- per-cell projections for diagonal d:
//   PI = H@Wi^T + bi + ins_bias ; PS = H@Ws^T + bs ; U = [H,C]^T Wbil
// Round-8 post-mortem: k-contiguous dwordx4 weight reads cut loads 16x but
// each still pays ~full memory latency (MLP~1: single look-ahead only hides
// ~150cy of the ~1500cy LLC/HBM latency; FETCH 8.7MB/dispatch shows weights
// aren't L2-resident). Fix: 8-deep register pipeline (wbuf[8] = 32 VGPRs,
// affordable now that a slot is a float4 chunk) + __launch_bounds__(256,2)
// for a 256-VGPR budget so the compiler can't serialize it.
// Block = 256 thr (4 waves x 16 j); lane = (jj = lane&15, kk = lane>>4)
// owns column j for k-quarter kk; 4-way k-split reduced by shfl_xor(16/32).
// grid.x = 96 j-groups of 64 (0-39: PI, 40-79: PS, 80-95: U), grid.y = m/8.
__global__ void __launch_bounds__(256, 2)
k_proj8(const float* __restrict__ Wi, const float* __restrict__ Ws,
        const float* __restrict__ WbilT, const float* __restrict__ bi,
        const float* __restrict__ bs,
        const float* __restrict__ cH, const float* __restrict__ cC,
        float* __restrict__ cPI, float* __restrict__ cPS, float* __restrict__ cU,
        int d, int P){
  __shared__ float As[8*512];   // [m][k], 16 KB
  const int t = threadIdx.x;
  const int g = blockIdx.x;
  const int m0 = blockIdx.y*8;
  const int Mtot = NB*P;
  const int nm = min(8, Mtot-m0);

  int kind, j0;
  if (g < 40){ kind=0; j0 = g*64; }
  else if (g < 80){ kind=1; j0 = (g-40)*64; }
  else { kind=2; j0 = (g-80)*64; }

  const int wave = t>>6, lane = t&63;
  const int jj = lane & 15, kk = lane >> 4;
  const int j = j0 + wave*16 + jj;

  int cells[8];
  #pragma unroll
  for (int m=0;m<8;m++){
    int mg = m0 + (m < nm ? m : 0);   // clamp dead rows to a valid cell
    int b = mg/P, i = mg%P;
    cells[m] = b*NCELL + coff(d) + i;
  }

  float acc[8];
  #pragma unroll
  for (int m=0;m<8;m++) acc[m] = 0.f;

  const int npass = (kind==2) ? 2 : 1;
  for (int pass=0; pass<npass; pass++){
    // stage 8 rows x 512 floats -> LDS [m][k]; 1024 float4s over 256 threads
    const float* __restrict__ srcbase = (kind==2 && pass==1) ? cC : cH;
    if (pass) __syncthreads();
    #pragma unroll
    for (int it=0; it<4; it++){
      int idx = t + it*256;
      int m = idx>>7, k4 = idx&127;
      ((float4*)As)[idx] = ((const float4*)(srcbase + (size_t)cells[m]*H))[k4];
    }
    __syncthreads();

    // this lane's contiguous k-run base (steps of 16 floats per chunk)
    const float* __restrict__ gk;
    if (kind==0)      gk = Wi    + (size_t)j*H  + kk*4;
    else if (kind==1) gk = Ws    + (size_t)j*H  + kk*4;
    else              gk = WbilT + (size_t)j*H2 + (size_t)pass*H + kk*4;

    // 8-deep software pipeline: 8 independent dwordx4 loads in flight
    float4 wbuf[8];
    #pragma unroll
    for (int c=0;c<8;c++) wbuf[c] = *(const float4*)(gk + c*16);
    #pragma unroll
    for (int c=0;c<32;c++){
      float4 wc = wbuf[c&7];
      if (c < 24) wbuf[c&7] = *(const float4*)(gk + (c+8)*16);
      const int kb = c*16 + kk*4;
      #pragma unroll
      for (int m=0;m<8;m++){
        float4 a = *(const float4*)&As[m*512 + kb];
        acc[m] = fmaf(a.x, wc.x, acc[m]);
        acc[m] = fmaf(a.y, wc.y, acc[m]);
        acc[m] = fmaf(a.z, wc.z, acc[m]);
        acc[m] = fmaf(a.w, wc.w, acc[m]);
      }
    }
  }

  // fold the 4-way k-split (lanes differing in bits 4,5)
  #pragma unroll
  for (int m=0;m<8;m++){
    acc[m] += __shfl_xor(acc[m], 16);
    acc[m] += __shfl_xor(acc[m], 32);
  }

  if (kk == 0){
    float bias = 0.f;
    if (kind==0) bias = bi[j] + ((j>=H && j<3*H)?1.f:0.f);   // ins_bias on [H,3H)
    else if (kind==1) bias = bs[j];
    for (int m=0;m<nm;m++){
      int cell = cells[m];
      if (kind==0)      cPI[(size_t)cell*H5 + j] = acc[m]+bias;
      else if (kind==1) cPS[(size_t)cell*H5 + j] = acc[m]+bias;
      else              cU [(size_t)cell*H2 + j] = acc[m];
    }
  }
}

// ---- combine diagonal L: one block per (b,left) span of length L+1
__global__ void k_combine(const float* __restrict__ cPI, const float* __restrict__ cPS,
                          const float* __restrict__ cU,
                          float* __restrict__ cH, float* __restrict__ cC, float* __restrict__ cS,
                          int L, int P){
  const int t = threadIdx.x;
  const int b = blockIdx.x / P;
  const int left = blockIdx.x % P;
  __shared__ float compat_s[32];
  __shared__ float wts_s[32];
  __shared__ float S_s;
  const int lane = t & 63;
  const int wv = t >> 6;
  // phase 1: compat_k = U[lcell] . [H;C][rcell] + lS + rS, waves parallel over k
  for (int k=wv; k<L; k+=4){
    int lc = b*NCELL + coff(k) + left;
    int rc = b*NCELL + coff(L-1-k) + left+k+1;
    const float* U  = cU + (size_t)lc*H2;
    const float* Hr = cH + (size_t)rc*H;
    const float* Cr = cC + (size_t)rc*H;
    float p = 0.f;
    for (int i=lane; i<H; i+=64)
      p += U[i]*Hr[i] + U[H+i]*Cr[i];
    #pragma unroll
    for (int off=32; off>0; off>>=1) p += __shfl_down(p, off);
    if (lane==0) compat_s[k] = p + cS[lc] + cS[rc];
  }
  __syncthreads();
  // phase 2: softmax over k (L<=23, serial on thread 0)
  if (t==0){
    float mx = -1e30f;
    for (int k=0;k<L;k++) mx = fmaxf(mx, compat_s[k]);
    float den = 0.f;
    for (int k=0;k<L;k++){ float e = __expf(compat_s[k]-mx); wts_s[k]=e; den+=e; }
    float inv = 1.f/den, S = 0.f;
    for (int k=0;k<L;k++){ wts_s[k]*=inv; S += wts_s[k]*compat_s[k]; }
    S_s = S;
  }
  __syncthreads();
  // phase 3: gates + weighted accumulate; thread t handles dims t and t+256
  float aH0=0.f, aH1=0.f, aC0=0.f, aC1=0.f;
  const int d0 = t, d1 = t+256;
  for (int k=0;k<L;k++){
    float wk = wts_s[k];
    int lc = b*NCELL + coff(k) + left;
    int rc = b*NCELL + coff(L-1-k) + left+k+1;
    const float* PI  = cPI + (size_t)lc*H5;
    const float* PS  = cPS + (size_t)rc*H5;
    const float* lCp = cC + (size_t)lc*H;
    const float* rCp = cC + (size_t)rc*H;
    {
      float p0 = PI[d0]     + PS[d0];
      float p1 = PI[H+d0]   + PS[H+d0];
      float p2 = PI[2*H+d0] + PS[2*H+d0];
      float p3 = PI[3*H+d0] + PS[3*H+d0];
      float p4 = PI[4*H+d0] + PS[4*H+d0];
      float mem = sigm(p1)*lCp[d0] + sigm(p2)*rCp[d0] + sigm(p0)*ftanh(p3);
      float h = sigm(p4)*ftanh(mem);
      aH0 += wk*h; aC0 += wk*mem;
    }
    {
      float p0 = PI[d1]     + PS[d1];
      float p1 = PI[H+d1]   + PS[H+d1];
      float p2 = PI[2*H+d1] + PS[2*H+d1];
      float p3 = PI[3*H+d1] + PS[3*H+d1];
      float p4 = PI[4*H+d1] + PS[4*H+d1];
      float mem = sigm(p1)*lCp[d1] + sigm(p2)*rCp[d1] + sigm(p0)*ftanh(p3);
      float h = sigm(p4)*ftanh(mem);
      aH1 += wk*h; aC1 += wk*mem;
    }
  }
  int nc = b*NCELL + coff(L) + left;
  cH[(size_t)nc*H + d0] = aH0; cH[(size_t)nc*H + d1] = aH1;
  cC[(size_t)nc*H + d0] = aC0; cC[(size_t)nc*H + d1] = aC1;
  if (t==0) cS[nc] = S_s;
}

// ---- root output: concat(H, C) of cell (0, n-1)
__global__ void k_out(const float* __restrict__ cH, const float* __restrict__ cC,
                      float* __restrict__ out){
  int tid = blockIdx.x*256+threadIdx.x;
  if (tid >= NB*H2) return;
  int b = tid>>10, d = tid&1023;
  int cell = b*NCELL + 299;   // coff(23)+0
  out[tid] = (d<H) ? cH[(size_t)cell*H + d] : cC[(size_t)cell*H + (d-H)];
}

extern "C" void kernel_launch(void* const* d_in, const int* in_sizes, int n_in,
                              void* d_out, int out_size, void* d_ws, size_t ws_size,
                              hipStream_t stream){
  const float* seqt = (const float*)d_in[0];
  const float* Wi   = (const float*)d_in[1];
  const float* bi   = (const float*)d_in[2];
  const float* Ws   = (const float*)d_in[3];
  const float* bs   = (const float*)d_in[4];
  const float* Wbil = (const float*)d_in[5];
  float* out = (float*)d_out;

  float* p = (ws_size >= NEED_BYTES && g_buf == nullptr) ? (float*)d_ws : g_buf;
  float* WbilT = p; p += (size_t)H2*H2;
  float* cH  = p; p += (size_t)NB*NCELL*H;
  float* cC  = p; p += (size_t)NB*NCELL*H;
  float* cS  = p; p += (size_t)NB*NCELL;
  float* cPI = p; p += (size_t)NB*NCELL*H5;
  float* cPS = p; p += (size_t)NB*NCELL*H5;
  float* cU  = p; p += (size_t)NB*NCELL*H2;

  k_transpose_bil<<<dim3(32,32), dim3(32,8), 0, stream>>>(Wbil, WbilT);
  k_leaf<<<(NB*NW*H+255)/256, 256, 0, stream>>>(seqt, cH, cC, cS);
  k_proj8<<<dim3(96, (NB*NW+7)/8), 256, 0, stream>>>(
      Wi, Ws, WbilT, bi, bs, cH, cC, cPI, cPS, cU, 0, NW);
  for (int L=1; L<NW; L++){
    int P = NW - L;
    k_combine<<<NB*P, 256, 0, stream>>>(cPI, cPS, cU, cH, cC, cS, L, P);
    if (L < NW-1)
      k_proj8<<<dim3(96, (NB*P+7)/8), 256, 0, stream>>>(
          Wi, Ws, WbilT, bi, bs, cH, cC, cPI, cPS, cU, L, P);
  }
  k_out<<<16, 256, 0, stream>>>(cH, cC, out);
}